// Round 1
// baseline (223.842 us; speedup 1.0000x reference)
//
#include <hip/hip_runtime.h>

#define B_ 2
#define N_ 192
#define DIM_ 512
#define H_ 8
#define DH_ 64
#define PROJ_ELEMS (B_*H_*N_*DH_)   // 196608

typedef __bf16 bf16_t;
typedef __bf16 bf16x8 __attribute__((ext_vector_type(8)));
typedef float  f32x4  __attribute__((ext_vector_type(4)));

__device__ __forceinline__ f32x4 mfma16(bf16x8 a, bf16x8 b, f32x4 c) {
    return __builtin_amdgcn_mfma_f32_16x16x32_bf16(a, b, c, 0, 0, 0);
}

struct ProjArgs {
    const float* src[4];
    const float* W[4];
    const float* bias[4];
    float scale[4];
};

// out[r,c] = (dot(src[r,:], W[c,:]) + bias[c]) * scale
// TO_BF16: scatter to [B,H,N,64] bf16 at outbase + pid*PROJ_ELEMS
// else:    row-major f32 [384,512]
template<bool TO_BF16>
__global__ __launch_bounds__(256) void gemm_bias_kernel(ProjArgs args, void* outbase) {
    const int pid = blockIdx.y;
    const float* __restrict__ A    = args.src[pid];
    const float* __restrict__ W    = args.W[pid];
    const float* __restrict__ bias = args.bias[pid];
    const float scale = args.scale[pid];

    const int rt = blockIdx.x >> 3;   // 12 row tiles of 32
    const int ct = blockIdx.x & 7;    // 8 col tiles of 64
    const int r0 = rt * 32, c0 = ct * 64;
    const int tx = threadIdx.x & 63;
    const int ty = threadIdx.x >> 6;  // 0..3
    const int c = c0 + tx;

    __shared__ __attribute__((aligned(16))) float As[32][132]; // pitch 132: 33*16B rows
    float acc[8] = {0,0,0,0,0,0,0,0};
    const float* Wr = W + (size_t)c * DIM_;

    for (int k0 = 0; k0 < DIM_; k0 += 128) {
        for (int ld = threadIdx.x; ld < 1024; ld += 256) {
            int rr = ld >> 5, c4 = ld & 31;
            float4 v = *(const float4*)(A + (size_t)(r0 + rr) * DIM_ + k0 + c4 * 4);
            *(float4*)&As[rr][c4 * 4] = v;
        }
        __syncthreads();
        #pragma unroll 8
        for (int k4 = 0; k4 < 32; ++k4) {
            float4 wv = *(const float4*)(Wr + k0 + k4 * 4);
            #pragma unroll
            for (int rr = 0; rr < 8; ++rr) {
                float4 av = *(const float4*)&As[ty * 8 + rr][k4 * 4]; // broadcast within wave
                acc[rr] += av.x * wv.x;
                acc[rr] += av.y * wv.y;
                acc[rr] += av.z * wv.z;
                acc[rr] += av.w * wv.w;
            }
        }
        __syncthreads();
    }
    const float bv = bias[c];
    #pragma unroll
    for (int rr = 0; rr < 8; ++rr) {
        int r = r0 + ty * 8 + rr;
        float val = (acc[rr] + bv) * scale;
        if (TO_BF16) {
            int b = r / N_, n = r - b * N_;
            int h = c >> 6, d = c & 63;
            ((bf16_t*)outbase)[(size_t)pid * PROJ_ELEMS +
                               (((size_t)(b * H_ + h)) * N_ + n) * DH_ + d] = (bf16_t)val;
        } else {
            ((float*)outbase)[(size_t)r * DIM_ + c] = val;
        }
    }
}

// Fused high-order attention.
// grid = (48 i-blocks, 16 bh). 4 waves/block, one i per wave.
// Per wave, for its i:  S = (q_i*K) @ L^T  (192x192, fp32 acc via MFMA 16x16x32)
//   E = exp(S) (no max-sub: |S| < ~0.7 for these inputs' scale), Z = sum(E)
//   T = E @ V  (through per-wave LDS buffer for the C->A layout transpose)
//   x[d] += v[j,d] * T[j,d]  summed over j; finally x/Z.
__global__ __launch_bounds__(256, 1) void attn_kernel(
    const bf16_t* __restrict__ Qg, const bf16_t* __restrict__ Kg,
    const bf16_t* __restrict__ Lg, const bf16_t* __restrict__ Vg,
    float* __restrict__ Xout)
{
    __shared__ __attribute__((aligned(16))) bf16_t Klds[192 * 72];   // [j][d], pitch 72
    __shared__ __attribute__((aligned(16))) bf16_t Llds[192 * 72];   // [k][d], pitch 72
    __shared__ __attribute__((aligned(16))) bf16_t VTlds[64 * 200];  // [d][k], pitch 200
    __shared__ __attribute__((aligned(16))) bf16_t Elds[4][16 * 216];// per-wave [j][k], pitch 216

    const int bh   = blockIdx.y;
    const int tid  = threadIdx.x;
    const int wid  = tid >> 6;
    const int lane = tid & 63;
    const int g    = lane >> 4;   // 0..3
    const int r16  = lane & 15;   // 0..15
    const size_t base = (size_t)bh * (N_ * DH_);

    // ---- stage K, L (row-major, 16B chunks) ----
    for (int idx = tid; idx < 1536; idx += 256) {
        int row = idx >> 3, dc = idx & 7;
        *(uint4*)&Klds[row * 72 + dc * 8] = *(const uint4*)(Kg + base + row * 64 + dc * 8);
        *(uint4*)&Llds[row * 72 + dc * 8] = *(const uint4*)(Lg + base + row * 64 + dc * 8);
    }
    // ---- stage V transposed: VT[d][j] ----
    for (int idx = tid; idx < 1536; idx += 256) {
        int dc = idx / 192;          // 0..7
        int j  = idx - dc * 192;     // 0..191
        bf16x8 v = *(const bf16x8*)(Vg + base + j * 64 + dc * 8);
        #pragma unroll
        for (int u = 0; u < 8; ++u)
            VTlds[(dc * 8 + u) * 200 + j] = v[u];
    }
    __syncthreads();

    // ---- resident B-fragments ----
    // L-frag [kt][ks]: B for S-GEMM: col k = kt*16+r16, kdim d = ks*32 + g*8 + u
    bf16x8 lf[12][2];
    #pragma unroll
    for (int kt = 0; kt < 12; ++kt)
        #pragma unroll
        for (int ks = 0; ks < 2; ++ks)
            lf[kt][ks] = *(const bf16x8*)&Llds[(kt * 16 + r16) * 72 + ks * 32 + g * 8];
    // V-frag [dt][ks]: B for T-GEMM: col d = dt*16+r16, kdim k = ks*32 + g*8 + u
    bf16x8 vf[4][6];
    #pragma unroll
    for (int dt = 0; dt < 4; ++dt)
        #pragma unroll
        for (int ks = 0; ks < 6; ++ks)
            vf[dt][ks] = *(const bf16x8*)&VTlds[(dt * 16 + r16) * 200 + ks * 32 + g * 8];

    const int i = blockIdx.x * 4 + wid;   // one i per wave

    // q_i values for this lane's A-frag slots (d = ks*32 + g*8 + u)
    float qv[2][8];
    {
        const bf16_t* qp = Qg + base + (size_t)i * 64;
        #pragma unroll
        for (int ks = 0; ks < 2; ++ks) {
            bf16x8 qb = *(const bf16x8*)(qp + ks * 32 + g * 8);
            #pragma unroll
            for (int u = 0; u < 8; ++u) qv[ks][u] = (float)qb[u];
        }
    }

    float xacc[4] = {0.f, 0.f, 0.f, 0.f};
    float Z = 0.f;
    bf16_t* Ew = Elds[wid];

    for (int jb = 0; jb < 12; ++jb) {   // j-strip of 16 rows
        // A-frags: A[j=jb*16+r16][d] = q[d]*k[j][d]
        bf16x8 af[2];
        #pragma unroll
        for (int ks = 0; ks < 2; ++ks) {
            bf16x8 kv = *(const bf16x8*)&Klds[(jb * 16 + r16) * 72 + ks * 32 + g * 8];
            #pragma unroll
            for (int u = 0; u < 8; ++u)
                af[ks][u] = (bf16_t)((float)kv[u] * qv[ks][u]);
        }
        // S strip: 12 k-tiles
        f32x4 c[12];
        #pragma unroll
        for (int kt = 0; kt < 12; ++kt) {
            f32x4 z4 = {0.f, 0.f, 0.f, 0.f};
            z4 = mfma16(af[0], lf[kt][0], z4);
            c[kt] = mfma16(af[1], lf[kt][1], z4);
        }
        // exp, Z, write E (C layout: row j = g*4+r, col k = kt*16+r16)
        #pragma unroll
        for (int kt = 0; kt < 12; ++kt) {
            #pragma unroll
            for (int r = 0; r < 4; ++r) {
                float e = __expf(c[kt][r]);
                Z += e;
                Ew[(g * 4 + r) * 216 + kt * 16 + r16] = (bf16_t)e;
            }
        }
        // T = E @ V : M=16 j, N=64 d, K=192 k
        f32x4 tc[4];
        #pragma unroll
        for (int dt = 0; dt < 4; ++dt) { f32x4 z4 = {0.f,0.f,0.f,0.f}; tc[dt] = z4; }
        #pragma unroll
        for (int ks = 0; ks < 6; ++ks) {
            bf16x8 ef = *(const bf16x8*)&Ew[r16 * 216 + ks * 32 + g * 8];
            #pragma unroll
            for (int dt = 0; dt < 4; ++dt)
                tc[dt] = mfma16(ef, vf[dt][ks], tc[dt]);
        }
        // x[d] += v[j,d] * T[j,d]; lane holds T[j=jb*16+g*4+r][d=dt*16+r16]
        #pragma unroll
        for (int dt = 0; dt < 4; ++dt) {
            #pragma unroll
            for (int r = 0; r < 4; ++r) {
                float vjd = (float)VTlds[(dt * 16 + r16) * 200 + jb * 16 + g * 4 + r];
                xacc[dt] += tc[dt][r] * vjd;
            }
        }
    }

    // reduce x over the 4 lane-groups (same r16)
    #pragma unroll
    for (int dt = 0; dt < 4; ++dt) {
        xacc[dt] += __shfl_xor(xacc[dt], 16);
        xacc[dt] += __shfl_xor(xacc[dt], 32);
    }
    // full-wave Z reduction
    Z += __shfl_xor(Z, 1);
    Z += __shfl_xor(Z, 2);
    Z += __shfl_xor(Z, 4);
    Z += __shfl_xor(Z, 8);
    Z += __shfl_xor(Z, 16);
    Z += __shfl_xor(Z, 32);
    const float invZ = 1.0f / Z;

    if (lane < 16) {
        const int b = bh >> 3, h = bh & 7;
        float* op = Xout + ((size_t)(b * N_ + i) * DIM_) + h * 64;
        #pragma unroll
        for (int dt = 0; dt < 4; ++dt)
            op[dt * 16 + lane] = xacc[dt] * invZ;
    }
}

extern "C" void kernel_launch(void* const* d_in, const int* in_sizes, int n_in,
                              void* d_out, int out_size, void* d_ws, size_t ws_size,
                              hipStream_t stream) {
    (void)in_sizes; (void)n_in; (void)out_size; (void)ws_size;
    const float* queries = (const float*)d_in[0];
    const float* keys    = (const float*)d_in[1];
    const float* values  = (const float*)d_in[2];
    const float* Wq = (const float*)d_in[3];
    const float* bq = (const float*)d_in[4];
    const float* Wk = (const float*)d_in[5];
    const float* bk = (const float*)d_in[6];
    const float* Wl = (const float*)d_in[7];
    const float* bl = (const float*)d_in[8];
    const float* Wv = (const float*)d_in[9];
    const float* bv = (const float*)d_in[10];
    const float* Wp = (const float*)d_in[11];
    const float* bp = (const float*)d_in[12];

    bf16_t* Qw = (bf16_t*)d_ws;                 // [B,H,N,64] bf16, q pre-scaled
    bf16_t* Kw = Qw + PROJ_ELEMS;
    bf16_t* Lw = Kw + PROJ_ELEMS;
    bf16_t* Vw = Lw + PROJ_ELEMS;
    float*  Xw = (float*)((char*)d_ws + 4 * (size_t)PROJ_ELEMS * sizeof(bf16_t)); // [384,512] f32

    // 1) projections q,k,l,v  (q scaled by Dh^-0.5)
    ProjArgs pa;
    pa.src[0] = queries; pa.W[0] = Wq; pa.bias[0] = bq; pa.scale[0] = 0.125f;
    pa.src[1] = keys;    pa.W[1] = Wk; pa.bias[1] = bk; pa.scale[1] = 1.0f;
    pa.src[2] = keys;    pa.W[2] = Wl; pa.bias[2] = bl; pa.scale[2] = 1.0f;
    pa.src[3] = values;  pa.W[3] = Wv; pa.bias[3] = bv; pa.scale[3] = 1.0f;
    gemm_bias_kernel<true><<<dim3(96, 4), 256, 0, stream>>>(pa, (void*)Qw);

    // 2) fused third-order attention -> Xw [384,512] f32 (heads merged)
    attn_kernel<<<dim3(48, 16), 256, 0, stream>>>(Qw, Kw, Lw, Vw, Xw);

    // 3) output projection
    ProjArgs fa;
    fa.src[0] = Xw; fa.W[0] = Wp; fa.bias[0] = bp; fa.scale[0] = 1.0f;
    fa.src[1] = Xw; fa.W[1] = Wp; fa.bias[1] = bp; fa.scale[1] = 1.0f;
    fa.src[2] = Xw; fa.W[2] = Wp; fa.bias[2] = bp; fa.scale[2] = 1.0f;
    fa.src[3] = Xw; fa.W[3] = Wp; fa.bias[3] = bp; fa.scale[3] = 1.0f;
    gemm_bias_kernel<false><<<dim3(96, 1), 256, 0, stream>>>(fa, d_out);
}

// Round 2
// 151.470 us; speedup vs baseline: 1.4778x; 1.4778x over previous
//
#include <hip/hip_runtime.h>

#define B_ 2
#define N_ 192
#define DIM_ 512
#define H_ 8
#define DH_ 64
#define PROJ_ELEMS (B_*H_*N_*DH_)   // 196608

typedef __bf16 bf16_t;
typedef __bf16 bf16x8 __attribute__((ext_vector_type(8)));
typedef float  f32x16 __attribute__((ext_vector_type(16)));

__device__ __forceinline__ f32x16 mfma32(bf16x8 a, bf16x8 b, f32x16 c) {
    return __builtin_amdgcn_mfma_f32_32x32x16_bf16(a, b, c, 0, 0, 0);
}

union U4 { unsigned int u[4]; bf16x8 v; };

__device__ __forceinline__ unsigned int pack_bf16(float a, float b) {
    unsigned short ua = __builtin_bit_cast(unsigned short, (bf16_t)a);
    unsigned short ub = __builtin_bit_cast(unsigned short, (bf16_t)b);
    return (unsigned int)ua | ((unsigned int)ub << 16);
}
__device__ __forceinline__ float bfbits(unsigned short u) {
    return (float)__builtin_bit_cast(bf16_t, u);
}

struct PArgs {
    const float* A[4];
    const float* W[4];
    const float* bias[4];
    float scale[4];
};

// 4 projections, bf16 MFMA. grid: 192 blocks x 256 thr; wave-tile 32x32, K=512.
// Output scattered to [mat][b,h][n][64] bf16.
__global__ __launch_bounds__(256) void proj4_kernel(PArgs args, bf16_t* out) {
    const int wid = threadIdx.x >> 6, lane = threadIdx.x & 63;
    const int lo = lane & 31, hi = lane >> 5;
    const int gt  = blockIdx.x * 4 + wid;     // 0..767
    const int mat = gt / 192, t = gt % 192;
    const int r0 = (t >> 4) * 32, c0 = (t & 15) * 32;
    const int c = c0 + lo;

    const float* __restrict__ arow = args.A[mat] + (size_t)(r0 + lo) * DIM_;
    const float* __restrict__ wrow = args.W[mat] + (size_t)c * DIM_;

    f32x16 acc = {};
    for (int k0 = 0; k0 < DIM_; k0 += 16) {
        const int kk = k0 + hi * 8;
        float4 a0 = *(const float4*)(arow + kk);
        float4 a1 = *(const float4*)(arow + kk + 4);
        float4 b0 = *(const float4*)(wrow + kk);
        float4 b1 = *(const float4*)(wrow + kk + 4);
        bf16x8 af, bf;
        af[0]=(bf16_t)a0.x; af[1]=(bf16_t)a0.y; af[2]=(bf16_t)a0.z; af[3]=(bf16_t)a0.w;
        af[4]=(bf16_t)a1.x; af[5]=(bf16_t)a1.y; af[6]=(bf16_t)a1.z; af[7]=(bf16_t)a1.w;
        bf[0]=(bf16_t)b0.x; bf[1]=(bf16_t)b0.y; bf[2]=(bf16_t)b0.z; bf[3]=(bf16_t)b0.w;
        bf[4]=(bf16_t)b1.x; bf[5]=(bf16_t)b1.y; bf[6]=(bf16_t)b1.z; bf[7]=(bf16_t)b1.w;
        acc = mfma32(af, bf, acc);
    }
    const float bv = args.bias[mat][c];
    const float sc = args.scale[mat];
    const int h = c >> 6, d = c & 63;
    #pragma unroll
    for (int r = 0; r < 16; ++r) {
        int row = r0 + (r & 3) + 8 * (r >> 2) + 4 * hi;
        int bb = (row >= N_) ? 1 : 0;
        int n = row - bb * N_;
        out[(size_t)mat * PROJ_ELEMS + (((size_t)(bb * H_ + h)) * N_ + n) * DH_ + d] =
            (bf16_t)((acc[r] + bv) * sc);
    }
}

// out-projection: d_out[r, c] = sum_k X[r,k] Wp[c,k] + bp[c], f32 out.
// grid: 48 blocks x 256; wave-tile 32x32.
__global__ __launch_bounds__(256) void outproj_kernel(const bf16_t* __restrict__ X,
                                                      const float* __restrict__ Wp,
                                                      const float* __restrict__ bp,
                                                      float* __restrict__ out) {
    const int wid = threadIdx.x >> 6, lane = threadIdx.x & 63;
    const int lo = lane & 31, hi = lane >> 5;
    const int gt = blockIdx.x * 4 + wid;      // 0..191
    const int r0 = (gt >> 4) * 32, c0 = (gt & 15) * 32;
    const int c = c0 + lo;

    const bf16_t* __restrict__ xrow = X + (size_t)(r0 + lo) * DIM_;
    const float*  __restrict__ wrow = Wp + (size_t)c * DIM_;

    f32x16 acc = {};
    for (int k0 = 0; k0 < DIM_; k0 += 16) {
        const int kk = k0 + hi * 8;
        bf16x8 af = *(const bf16x8*)(xrow + kk);
        float4 b0 = *(const float4*)(wrow + kk);
        float4 b1 = *(const float4*)(wrow + kk + 4);
        bf16x8 bf;
        bf[0]=(bf16_t)b0.x; bf[1]=(bf16_t)b0.y; bf[2]=(bf16_t)b0.z; bf[3]=(bf16_t)b0.w;
        bf[4]=(bf16_t)b1.x; bf[5]=(bf16_t)b1.y; bf[6]=(bf16_t)b1.z; bf[7]=(bf16_t)b1.w;
        acc = mfma32(af, bf, acc);
    }
    const float bv = bp[c];
    #pragma unroll
    for (int r = 0; r < 16; ++r) {
        int row = r0 + (r & 3) + 8 * (r >> 2) + 4 * hi;
        out[(size_t)row * DIM_ + c] = acc[r] + bv;
    }
}

// Fused third-order attention, 32x32 MFMA + in-register E transpose.
// grid (48, 16) x 256 thr; one i per wave; LDS = L (192x72) + V^T (64x200) = 53.2KB
// -> 3 blocks/CU, 12 waves/CU. q was pre-scaled by SCALE*log2(e), so exp2 == exp.
__global__ __launch_bounds__(256, 3) void attn_kernel(
    const bf16_t* __restrict__ Qg, const bf16_t* __restrict__ Kg,
    const bf16_t* __restrict__ Lg, const bf16_t* __restrict__ Vg,
    bf16_t* __restrict__ Xout)
{
    __shared__ __attribute__((aligned(16))) bf16_t Llds[192 * 72];   // [k][d] pitch 72
    __shared__ __attribute__((aligned(16))) bf16_t VTlds[64 * 200];  // [d][k] pitch 200

    const int bh = blockIdx.y;
    const int tid = threadIdx.x, wid = tid >> 6, lane = tid & 63;
    const int lo = lane & 31, hi = lane >> 5;
    const size_t base = (size_t)bh * (N_ * DH_);

    for (int idx = tid; idx < 1536; idx += 256) {
        int row = idx >> 3, ch = idx & 7;
        *(uint4*)&Llds[row * 72 + ch * 8] = *(const uint4*)(Lg + base + row * 64 + ch * 8);
    }
    for (int idx = tid; idx < 1536; idx += 256) {
        int dc = idx / 192, j = idx - dc * 192;
        bf16x8 v = *(const bf16x8*)(Vg + base + (size_t)j * 64 + dc * 8);
        #pragma unroll
        for (int u = 0; u < 8; ++u)
            VTlds[(dc * 8 + u) * 200 + j] = v[u];
    }
    __syncthreads();

    const int i = blockIdx.x * 4 + wid;
    const bf16_t* qp = Qg + base + (size_t)i * 64;
    bf16x8 qb[4];
    #pragma unroll
    for (int s = 0; s < 4; ++s) qb[s] = *(const bf16x8*)(qp + s * 16 + hi * 8);

    float xacc0 = 0.f, xacc1 = 0.f;
    float Zp[4] = {0.f, 0.f, 0.f, 0.f};

    for (int jb = 0; jb < 6; ++jb) {
        // B-frags for S^T: (q .* K)[j = lo + jb*32][d], from global (L2-hot)
        bf16x8 bq[4];
        const bf16_t* kp = Kg + base + (size_t)(jb * 32 + lo) * 64;
        #pragma unroll
        for (int s = 0; s < 4; ++s) {
            bf16x8 kv = *(const bf16x8*)(kp + s * 16 + hi * 8);
            bf16x8 t;
            #pragma unroll
            for (int u = 0; u < 8; ++u) t[u] = (bf16_t)((float)kv[u] * (float)qb[s][u]);
            bq[s] = t;
        }

        f32x16 Tc0 = {}, Tc1 = {};
        #pragma unroll
        for (int kh = 0; kh < 2; ++kh) {
            // S^T[k = kh*96 + kt*32 + rows][j = jb*32 + lo], K-dim d = 64
            f32x16 Sc[3];
            #pragma unroll
            for (int kt = 0; kt < 3; ++kt) {
                f32x16 a = {};
                #pragma unroll
                for (int s = 0; s < 4; ++s) {
                    bf16x8 lf = *(const bf16x8*)&Llds[(kh * 96 + kt * 32 + lo) * 72 + s * 16 + hi * 8];
                    a = mfma32(lf, bq[s], a);
                }
                Sc[kt] = a;
            }
            #pragma unroll
            for (int kt = 0; kt < 3; ++kt) {
                float e[16];
                #pragma unroll
                for (int r = 0; r < 16; ++r) {
                    e[r] = __builtin_amdgcn_exp2f(Sc[kt][r]);
                    Zp[r & 3] += e[r];
                }
                #pragma unroll
                for (int sg = 0; sg < 2; ++sg) {
                    // build E A-frag (rows j=lo, k-slice 16) via permlane32_swap
                    unsigned int x0 = pack_bf16(e[8*sg+0], e[8*sg+1]);
                    unsigned int x1 = pack_bf16(e[8*sg+2], e[8*sg+3]);
                    unsigned int y0 = pack_bf16(e[8*sg+4], e[8*sg+5]);
                    unsigned int y1 = pack_bf16(e[8*sg+6], e[8*sg+7]);
                    asm volatile("v_permlane32_swap_b32 %0, %1\n\t"
                                 "v_permlane32_swap_b32 %2, %3"
                                 : "+v"(x0), "+v"(y0), "+v"(x1), "+v"(y1));
                    U4 uf; uf.u[0] = x0; uf.u[1] = x1; uf.u[2] = y0; uf.u[3] = y1;
                    const int tg = kh * 6 + kt * 2 + sg;     // k-step 0..11
                    bf16x8 vf0 = *(const bf16x8*)&VTlds[(0 * 32 + lo) * 200 + tg * 16 + hi * 8];
                    Tc0 = mfma32(uf.v, vf0, Tc0);
                    bf16x8 vf1 = *(const bf16x8*)&VTlds[(1 * 32 + lo) * 200 + tg * 16 + hi * 8];
                    Tc1 = mfma32(uf.v, vf1, Tc1);
                }
            }
        }
        // x[d] += v[j,d] * T[j,d] over this strip's 32 j
        #pragma unroll
        for (int m = 0; m < 4; ++m) {
            const int jj = jb * 32 + m * 8 + 4 * hi;
            ushort4 v0 = *(const ushort4*)&VTlds[(0 * 32 + lo) * 200 + jj];
            ushort4 v1 = *(const ushort4*)&VTlds[(1 * 32 + lo) * 200 + jj];
            xacc0 += Tc0[m*4+0]*bfbits(v0.x) + Tc0[m*4+1]*bfbits(v0.y)
                   + Tc0[m*4+2]*bfbits(v0.z) + Tc0[m*4+3]*bfbits(v0.w);
            xacc1 += Tc1[m*4+0]*bfbits(v1.x) + Tc1[m*4+1]*bfbits(v1.y)
                   + Tc1[m*4+2]*bfbits(v1.z) + Tc1[m*4+3]*bfbits(v1.w);
        }
    }

    float Z = (Zp[0] + Zp[1]) + (Zp[2] + Zp[3]);
    Z += __shfl_xor(Z, 1);
    Z += __shfl_xor(Z, 2);
    Z += __shfl_xor(Z, 4);
    Z += __shfl_xor(Z, 8);
    Z += __shfl_xor(Z, 16);
    Z += __shfl_xor(Z, 32);
    xacc0 += __shfl_xor(xacc0, 32);
    xacc1 += __shfl_xor(xacc1, 32);
    const float invZ = 1.0f / Z;

    if (hi == 0) {
        const int b = bh >> 3, h = bh & 7;
        bf16_t* op = Xout + ((size_t)(b * N_ + i) * DIM_) + h * 64;
        op[lo]      = (bf16_t)(xacc0 * invZ);
        op[32 + lo] = (bf16_t)(xacc1 * invZ);
    }
}

extern "C" void kernel_launch(void* const* d_in, const int* in_sizes, int n_in,
                              void* d_out, int out_size, void* d_ws, size_t ws_size,
                              hipStream_t stream) {
    (void)in_sizes; (void)n_in; (void)out_size; (void)ws_size;
    const float* queries = (const float*)d_in[0];
    const float* keys    = (const float*)d_in[1];
    const float* values  = (const float*)d_in[2];
    const float* Wq = (const float*)d_in[3];
    const float* bq = (const float*)d_in[4];
    const float* Wk = (const float*)d_in[5];
    const float* bk = (const float*)d_in[6];
    const float* Wl = (const float*)d_in[7];
    const float* bl = (const float*)d_in[8];
    const float* Wv = (const float*)d_in[9];
    const float* bv = (const float*)d_in[10];
    const float* Wp = (const float*)d_in[11];
    const float* bp = (const float*)d_in[12];

    bf16_t* Qw = (bf16_t*)d_ws;                 // [B,H,N,64] bf16, q pre-scaled by SCALE*log2e
    bf16_t* Xw = Qw + 4 * (size_t)PROJ_ELEMS;   // [384,512] bf16 attention output

    PArgs pa;
    pa.A[0] = queries; pa.W[0] = Wq; pa.bias[0] = bq; pa.scale[0] = 0.125f * 1.44269504f;
    pa.A[1] = keys;    pa.W[1] = Wk; pa.bias[1] = bk; pa.scale[1] = 1.0f;
    pa.A[2] = keys;    pa.W[2] = Wl; pa.bias[2] = bl; pa.scale[2] = 1.0f;
    pa.A[3] = values;  pa.W[3] = Wv; pa.bias[3] = bv; pa.scale[3] = 1.0f;
    proj4_kernel<<<dim3(192), 256, 0, stream>>>(pa, Qw);

    attn_kernel<<<dim3(48, 16), 256, 0, stream>>>(
        Qw, Qw + PROJ_ELEMS, Qw + 2 * (size_t)PROJ_ELEMS, Qw + 3 * (size_t)PROJ_ELEMS, Xw);

    outproj_kernel<<<dim3(48), 256, 0, stream>>>(Xw, Wp, bp, (float*)d_out);
}

// Round 3
// 137.078 us; speedup vs baseline: 1.6330x; 1.1050x over previous
//
#include <hip/hip_runtime.h>

#define B_ 2
#define N_ 192
#define DIM_ 512
#define H_ 8
#define DH_ 64
#define PROJ_ELEMS (B_*H_*N_*DH_)   // 196608
#define W_ELEMS (DIM_*DIM_)         // 262144
#define A_ELEMS (B_*N_*DIM_)        // 196608

typedef __bf16 bf16_t;
typedef __bf16 bf16x4 __attribute__((ext_vector_type(4)));
typedef __bf16 bf16x8 __attribute__((ext_vector_type(8)));
typedef float  f32x16 __attribute__((ext_vector_type(16)));

__device__ __forceinline__ f32x16 mfma32(bf16x8 a, bf16x8 b, f32x16 c) {
    return __builtin_amdgcn_mfma_f32_32x32x16_bf16(a, b, c, 0, 0, 0);
}

union U4 { unsigned int u[4]; bf16x8 v; };

__device__ __forceinline__ unsigned int pack_bf16(float a, float b) {
    unsigned short ua = __builtin_bit_cast(unsigned short, (bf16_t)a);
    unsigned short ub = __builtin_bit_cast(unsigned short, (bf16_t)b);
    return (unsigned int)ua | ((unsigned int)ub << 16);
}
__device__ __forceinline__ float bfbits(unsigned short u) {
    return (float)__builtin_bit_cast(bf16_t, u);
}

// ---------------- f32 -> bf16 conversion ----------------
struct CArgs {
    const float* src[8];
    bf16_t* dst[8];
    int n[8];
};
__global__ __launch_bounds__(256) void cvt_kernel(CArgs a) {
    const int s = blockIdx.y;
    const int i = (blockIdx.x * 256 + threadIdx.x) * 4;
    if (i < a.n[s]) {
        float4 v = *(const float4*)(a.src[s] + i);
        bf16x4 o;
        o[0] = (bf16_t)v.x; o[1] = (bf16_t)v.y; o[2] = (bf16_t)v.z; o[3] = (bf16_t)v.w;
        *(bf16x4*)(a.dst[s] + i) = o;
    }
}

// ---------------- unified 64x64-tile bf16 GEMM ----------------
// out[r,c] = sum_k A[r,k] * B[c,k] (+bias[c]) (*scale)
// MODE 0: scatter bf16 to [mat][b,h][n][64];  MODE 1: f32 row-major [384][512]
struct GArgs {
    const bf16_t* A[4];
    const bf16_t* Bm[4];
    const float* bias[4];
    float scale[4];
};

template<int MODE>
__global__ __launch_bounds__(256) void gemm64_kernel(GArgs g, void* outp) {
    const int mat = blockIdx.y;
    const bf16_t* __restrict__ A  = g.A[mat];
    const bf16_t* __restrict__ Bm = g.Bm[mat];

    const int rt = blockIdx.x >> 3, ct = blockIdx.x & 7;
    const int r0 = rt * 64, c0 = ct * 64;
    const int tid = threadIdx.x, wid = tid >> 6, lane = tid & 63;
    const int lo = lane & 31, hi = lane >> 5;
    const int wr = wid >> 1, wc = wid & 1;

    __shared__ __attribute__((aligned(16))) bf16_t As[64 * 64];
    __shared__ __attribute__((aligned(16))) bf16_t Bs[64 * 64];

    f32x16 acc = {};
    for (int k0 = 0; k0 < DIM_; k0 += 64) {
        // stage A,B tiles: linear LDS dest, XOR-pre-swizzled global source
        #pragma unroll
        for (int cch = 0; cch < 2; ++cch) {
            const int d = wid * 2048 + cch * 1024 + lane * 16;   // dest byte in tile
            const int r = d >> 7;                                 // tile row
            const int off = (d ^ ((r & 7) << 4)) & 127;           // swizzled byte in row
            const char* srcA = (const char*)A + (size_t)(r0 + r) * (DIM_ * 2) + k0 * 2 + off;
            const char* srcB = (const char*)Bm + (size_t)(c0 + r) * (DIM_ * 2) + k0 * 2 + off;
            __builtin_amdgcn_global_load_lds(
                (const __attribute__((address_space(1))) void*)srcA,
                (__attribute__((address_space(3))) void*)((char*)As + wid * 2048 + cch * 1024),
                16, 0, 0);
            __builtin_amdgcn_global_load_lds(
                (const __attribute__((address_space(1))) void*)srcB,
                (__attribute__((address_space(3))) void*)((char*)Bs + wid * 2048 + cch * 1024),
                16, 0, 0);
        }
        __syncthreads();
        const int rowA = wr * 32 + lo, rowB = wc * 32 + lo;
        #pragma unroll
        for (int s = 0; s < 4; ++s) {
            const int ka = (rowA * 128 + s * 32 + hi * 16) ^ ((rowA & 7) << 4);
            const int kb = (rowB * 128 + s * 32 + hi * 16) ^ ((rowB & 7) << 4);
            bf16x8 af = *(const bf16x8*)((const char*)As + ka);
            bf16x8 bf = *(const bf16x8*)((const char*)Bs + kb);
            acc = mfma32(af, bf, acc);
        }
        __syncthreads();
    }

    const int c = c0 + wc * 32 + lo;
    const float bv = g.bias[mat][c];
    if (MODE == 0) {
        const float sc = g.scale[mat];
        const int h = c >> 6, dd = c & 63;
        bf16_t* out = (bf16_t*)outp + (size_t)mat * PROJ_ELEMS;
        #pragma unroll
        for (int r = 0; r < 16; ++r) {
            int row = r0 + wr * 32 + (r & 3) + 8 * (r >> 2) + 4 * hi;
            int bb = (row >= N_) ? 1 : 0;
            int n = row - bb * N_;
            out[(((size_t)(bb * H_ + h)) * N_ + n) * DH_ + dd] = (bf16_t)((acc[r] + bv) * sc);
        }
    } else {
        float* out = (float*)outp;
        #pragma unroll
        for (int r = 0; r < 16; ++r) {
            int row = r0 + wr * 32 + (r & 3) + 8 * (r >> 2) + 4 * hi;
            out[(size_t)row * DIM_ + c] = acc[r] + bv;
        }
    }
}

// ---------------- fused third-order attention (unchanged from round 2) ----------------
__global__ __launch_bounds__(256, 3) void attn_kernel(
    const bf16_t* __restrict__ Qg, const bf16_t* __restrict__ Kg,
    const bf16_t* __restrict__ Lg, const bf16_t* __restrict__ Vg,
    bf16_t* __restrict__ Xout)
{
    __shared__ __attribute__((aligned(16))) bf16_t Llds[192 * 72];   // [k][d] pitch 72
    __shared__ __attribute__((aligned(16))) bf16_t VTlds[64 * 200];  // [d][k] pitch 200

    const int bh = blockIdx.y;
    const int tid = threadIdx.x, wid = tid >> 6, lane = tid & 63;
    const int lo = lane & 31, hi = lane >> 5;
    const size_t base = (size_t)bh * (N_ * DH_);

    for (int idx = tid; idx < 1536; idx += 256) {
        int row = idx >> 3, ch = idx & 7;
        *(uint4*)&Llds[row * 72 + ch * 8] = *(const uint4*)(Lg + base + row * 64 + ch * 8);
    }
    for (int idx = tid; idx < 1536; idx += 256) {
        int dc = idx / 192, j = idx - dc * 192;
        bf16x8 v = *(const bf16x8*)(Vg + base + (size_t)j * 64 + dc * 8);
        #pragma unroll
        for (int u = 0; u < 8; ++u)
            VTlds[(dc * 8 + u) * 200 + j] = v[u];
    }
    __syncthreads();

    const int i = blockIdx.x * 4 + wid;
    const bf16_t* qp = Qg + base + (size_t)i * 64;
    bf16x8 qb[4];
    #pragma unroll
    for (int s = 0; s < 4; ++s) qb[s] = *(const bf16x8*)(qp + s * 16 + hi * 8);

    float xacc0 = 0.f, xacc1 = 0.f;
    float Zp[4] = {0.f, 0.f, 0.f, 0.f};

    for (int jb = 0; jb < 6; ++jb) {
        bf16x8 bq[4];
        const bf16_t* kp = Kg + base + (size_t)(jb * 32 + lo) * 64;
        #pragma unroll
        for (int s = 0; s < 4; ++s) {
            bf16x8 kv = *(const bf16x8*)(kp + s * 16 + hi * 8);
            bf16x8 t;
            #pragma unroll
            for (int u = 0; u < 8; ++u) t[u] = (bf16_t)((float)kv[u] * (float)qb[s][u]);
            bq[s] = t;
        }

        f32x16 Tc0 = {}, Tc1 = {};
        #pragma unroll
        for (int kh = 0; kh < 2; ++kh) {
            f32x16 Sc[3];
            #pragma unroll
            for (int kt = 0; kt < 3; ++kt) {
                f32x16 a = {};
                #pragma unroll
                for (int s = 0; s < 4; ++s) {
                    bf16x8 lf = *(const bf16x8*)&Llds[(kh * 96 + kt * 32 + lo) * 72 + s * 16 + hi * 8];
                    a = mfma32(lf, bq[s], a);
                }
                Sc[kt] = a;
            }
            #pragma unroll
            for (int kt = 0; kt < 3; ++kt) {
                float e[16];
                #pragma unroll
                for (int r = 0; r < 16; ++r) {
                    e[r] = __builtin_amdgcn_exp2f(Sc[kt][r]);
                    Zp[r & 3] += e[r];
                }
                #pragma unroll
                for (int sg = 0; sg < 2; ++sg) {
                    unsigned int x0 = pack_bf16(e[8*sg+0], e[8*sg+1]);
                    unsigned int x1 = pack_bf16(e[8*sg+2], e[8*sg+3]);
                    unsigned int y0 = pack_bf16(e[8*sg+4], e[8*sg+5]);
                    unsigned int y1 = pack_bf16(e[8*sg+6], e[8*sg+7]);
                    asm volatile("v_permlane32_swap_b32 %0, %1\n\t"
                                 "v_permlane32_swap_b32 %2, %3"
                                 : "+v"(x0), "+v"(y0), "+v"(x1), "+v"(y1));
                    U4 uf; uf.u[0] = x0; uf.u[1] = x1; uf.u[2] = y0; uf.u[3] = y1;
                    const int tg = kh * 6 + kt * 2 + sg;
                    bf16x8 vf0 = *(const bf16x8*)&VTlds[(0 * 32 + lo) * 200 + tg * 16 + hi * 8];
                    Tc0 = mfma32(uf.v, vf0, Tc0);
                    bf16x8 vf1 = *(const bf16x8*)&VTlds[(1 * 32 + lo) * 200 + tg * 16 + hi * 8];
                    Tc1 = mfma32(uf.v, vf1, Tc1);
                }
            }
        }
        #pragma unroll
        for (int m = 0; m < 4; ++m) {
            const int jj = jb * 32 + m * 8 + 4 * hi;
            ushort4 v0 = *(const ushort4*)&VTlds[(0 * 32 + lo) * 200 + jj];
            ushort4 v1 = *(const ushort4*)&VTlds[(1 * 32 + lo) * 200 + jj];
            xacc0 += Tc0[m*4+0]*bfbits(v0.x) + Tc0[m*4+1]*bfbits(v0.y)
                   + Tc0[m*4+2]*bfbits(v0.z) + Tc0[m*4+3]*bfbits(v0.w);
            xacc1 += Tc1[m*4+0]*bfbits(v1.x) + Tc1[m*4+1]*bfbits(v1.y)
                   + Tc1[m*4+2]*bfbits(v1.z) + Tc1[m*4+3]*bfbits(v1.w);
        }
    }

    float Z = (Zp[0] + Zp[1]) + (Zp[2] + Zp[3]);
    Z += __shfl_xor(Z, 1);
    Z += __shfl_xor(Z, 2);
    Z += __shfl_xor(Z, 4);
    Z += __shfl_xor(Z, 8);
    Z += __shfl_xor(Z, 16);
    Z += __shfl_xor(Z, 32);
    xacc0 += __shfl_xor(xacc0, 32);
    xacc1 += __shfl_xor(xacc1, 32);
    const float invZ = 1.0f / Z;

    if (hi == 0) {
        const int b = bh >> 3, h = bh & 7;
        bf16_t* op = Xout + ((size_t)(b * N_ + i) * DIM_) + h * 64;
        op[lo]      = (bf16_t)(xacc0 * invZ);
        op[32 + lo] = (bf16_t)(xacc1 * invZ);
    }
}

extern "C" void kernel_launch(void* const* d_in, const int* in_sizes, int n_in,
                              void* d_out, int out_size, void* d_ws, size_t ws_size,
                              hipStream_t stream) {
    (void)in_sizes; (void)n_in; (void)out_size; (void)ws_size;
    const float* queries = (const float*)d_in[0];
    const float* keys    = (const float*)d_in[1];
    const float* values  = (const float*)d_in[2];
    const float* Wq = (const float*)d_in[3];
    const float* bq = (const float*)d_in[4];
    const float* Wk = (const float*)d_in[5];
    const float* bk = (const float*)d_in[6];
    const float* Wl = (const float*)d_in[7];
    const float* bl = (const float*)d_in[8];
    const float* Wv = (const float*)d_in[9];
    const float* bv = (const float*)d_in[10];
    const float* Wp = (const float*)d_in[11];
    const float* bp = (const float*)d_in[12];

    // ws layout (bf16 elems)
    bf16_t* Abf = (bf16_t*)d_ws;                    // 3 x 196608 (queries, keys, values)
    bf16_t* Wbf = Abf + 3 * (size_t)A_ELEMS;        // 5 x 262144 (Wq, Wk, Wl, Wv, Wp)
    bf16_t* Pw  = Wbf + 5 * (size_t)W_ELEMS;        // 4 x 196608 (Q,K,L,V projected)
    bf16_t* Xw  = Pw  + 4 * (size_t)PROJ_ELEMS;     // 196608 attention out (bf16)

    // 1) convert activations + weights to bf16
    CArgs ca;
    ca.src[0] = queries; ca.dst[0] = Abf;               ca.n[0] = A_ELEMS;
    ca.src[1] = keys;    ca.dst[1] = Abf + A_ELEMS;     ca.n[1] = A_ELEMS;
    ca.src[2] = values;  ca.dst[2] = Abf + 2*A_ELEMS;   ca.n[2] = A_ELEMS;
    ca.src[3] = Wq;      ca.dst[3] = Wbf;               ca.n[3] = W_ELEMS;
    ca.src[4] = Wk;      ca.dst[4] = Wbf + W_ELEMS;     ca.n[4] = W_ELEMS;
    ca.src[5] = Wl;      ca.dst[5] = Wbf + 2*W_ELEMS;   ca.n[5] = W_ELEMS;
    ca.src[6] = Wv;      ca.dst[6] = Wbf + 3*W_ELEMS;   ca.n[6] = W_ELEMS;
    ca.src[7] = Wp;      ca.dst[7] = Wbf + 4*W_ELEMS;   ca.n[7] = W_ELEMS;
    cvt_kernel<<<dim3(256, 8), 256, 0, stream>>>(ca);

    // 2) four projections (q scaled by SCALE*log2e for exp2-based softmax)
    GArgs pa;
    pa.A[0] = Abf;             pa.Bm[0] = Wbf;             pa.bias[0] = bq; pa.scale[0] = 0.125f * 1.44269504f;
    pa.A[1] = Abf + A_ELEMS;   pa.Bm[1] = Wbf + W_ELEMS;   pa.bias[1] = bk; pa.scale[1] = 1.0f;
    pa.A[2] = Abf + A_ELEMS;   pa.Bm[2] = Wbf + 2*W_ELEMS; pa.bias[2] = bl; pa.scale[2] = 1.0f;
    pa.A[3] = Abf + 2*A_ELEMS; pa.Bm[3] = Wbf + 3*W_ELEMS; pa.bias[3] = bv; pa.scale[3] = 1.0f;
    gemm64_kernel<0><<<dim3(48, 4), 256, 0, stream>>>(pa, (void*)Pw);

    // 3) fused third-order attention
    attn_kernel<<<dim3(48, 16), 256, 0, stream>>>(
        Pw, Pw + PROJ_ELEMS, Pw + 2 * (size_t)PROJ_ELEMS, Pw + 3 * (size_t)PROJ_ELEMS, Xw);

    // 4) output projection (f32 out)
    GArgs fa;
    fa.A[0] = Xw; fa.Bm[0] = Wbf + 4*W_ELEMS; fa.bias[0] = bp; fa.scale[0] = 1.0f;
    fa.A[1] = fa.A[0]; fa.Bm[1] = fa.Bm[0]; fa.bias[1] = fa.bias[0]; fa.scale[1] = 1.0f;
    fa.A[2] = fa.A[0]; fa.Bm[2] = fa.Bm[0]; fa.bias[2] = fa.bias[0]; fa.scale[2] = 1.0f;
    fa.A[3] = fa.A[0]; fa.Bm[3] = fa.Bm[0]; fa.bias[3] = fa.bias[0]; fa.scale[3] = 1.0f;
    gemm64_kernel<1><<<dim3(48, 1), 256, 0, stream>>>(fa, d_out);
}